// Round 6
// baseline (3367.055 us; speedup 1.0000x reference)
//
#include <hip/hip_runtime.h>
#include <hip/hip_bf16.h>
#include <math.h>

// Problem dims
#define B_  32
#define T_  512
#define D_  128
#define N_  1024
#define NOISE_ 0.001f

#define NWORK 64          // recurrence worker blocks; each owns N_/NWORK = 16 columns
#define CPB   16          // columns per block
#define GRID_REC 256      // 64 workers + 192 heater blocks (1 block/CU)

typedef __attribute__((ext_vector_type(8))) short  bf16x8;
typedef __attribute__((ext_vector_type(4))) float  f32x4;
typedef __attribute__((ext_vector_type(2))) float  f32x2;
typedef __attribute__((ext_vector_type(4))) int    i32x4;

static __device__ __forceinline__ unsigned short f2bf_rn(float f) {
    unsigned int u = __builtin_bit_cast(unsigned int, f);
    unsigned int r = (u + 0x7FFFu + ((u >> 16) & 1u)) >> 16;
    return (unsigned short)r;
}
static __device__ __forceinline__ float bf2f(unsigned short h) {
    return __builtin_bit_cast(float, (unsigned int)h << 16);
}
static __device__ __forceinline__ int imin(int a, int b) { return a < b ? a : b; }

// ---------------------------------------------------------------------------
// Kernel A: xin = (x @ w_input) * scale, written INTO d_out at [b][t][n].
// (unchanged, verified)
// ---------------------------------------------------------------------------
__global__ __launch_bounds__(256) void xin_gemm(
    const float* __restrict__ x, const float* __restrict__ w_in,
    const float* __restrict__ scale_p, float* __restrict__ out) {
  __shared__ float As[64 * 132];
  __shared__ float Bs[128 * 68];
  const int tid = threadIdx.x;
  const int bm = blockIdx.x;       // 0..255
  const int bn = blockIdx.y;       // 0..15

  {
    const f32x4* xg = (const f32x4*)(x + (size_t)bm * 64 * 128);
#pragma unroll
    for (int i = 0; i < 8; ++i) {
      int idx = tid + i * 256;
      int r = idx >> 5, c4 = idx & 31;
      f32x4 v = xg[idx];
      float* dst = &As[r * 132 + c4 * 4];
      dst[0] = v.x; dst[1] = v.y; dst[2] = v.z; dst[3] = v.w;
    }
  }
  {
#pragma unroll
    for (int i = 0; i < 8; ++i) {
      int idx = tid + i * 256;
      int r = idx >> 4, c4 = idx & 15;
      f32x4 v = *(const f32x4*)(w_in + (size_t)r * N_ + bn * 64 + c4 * 4);
      float* dst = &Bs[r * 68 + c4 * 4];
      dst[0] = v.x; dst[1] = v.y; dst[2] = v.z; dst[3] = v.w;
    }
  }
  __syncthreads();

  const int tx = tid & 15, ty = tid >> 4;
  float acc[4][4] = {};
  for (int k = 0; k < 128; ++k) {
    float a0 = As[(ty * 4 + 0) * 132 + k];
    float a1 = As[(ty * 4 + 1) * 132 + k];
    float a2 = As[(ty * 4 + 2) * 132 + k];
    float a3 = As[(ty * 4 + 3) * 132 + k];
    f32x4 bv = *(const f32x4*)&Bs[k * 68 + tx * 4];
#pragma unroll
    for (int j = 0; j < 4; ++j) {
      acc[0][j] += a0 * bv[j];
      acc[1][j] += a1 * bv[j];
      acc[2][j] += a2 * bv[j];
      acc[3][j] += a3 * bv[j];
    }
  }
  const float s = scale_p[0];
#pragma unroll
  for (int i = 0; i < 4; ++i) {
    int row = bm * 64 + ty * 4 + i;
    if ((row & 511) == 0) continue;
    f32x4 o;
    o.x = acc[i][0] * s; o.y = acc[i][1] * s;
    o.z = acc[i][2] * s; o.w = acc[i][3] * s;
    *(f32x4*)(out + (size_t)row * N_ + bn * 64 + tx * 4) = o;
  }
}

// ---------------------------------------------------------------------------
// Kernel B: out[:,0,:] = step0 ; states0 -> compensated bf16 ping buffer 0 ;
// zero flags. Flag layout (ints): producer block p owns [p*16 .. p*16+15]
// (one 64B line); wave-flags packed at [p*16 + w], w=0..3.
// ---------------------------------------------------------------------------
__global__ __launch_bounds__(256) void init_k(
    const float* __restrict__ states0, const float* __restrict__ step0,
    float* __restrict__ out, unsigned short* __restrict__ st_hi,
    unsigned short* __restrict__ st_lo, int* __restrict__ flags) {
  int i = blockIdx.x * 256 + threadIdx.x;
  if (i < B_ * N_) {
    int b = i >> 10, n = i & 1023;
    out[((size_t)b * T_ + 0) * N_ + n] = step0[i];
    float sv = states0[i];
    unsigned short h = f2bf_rn(sv);
    st_hi[i] = h;
    st_lo[i] = f2bf_rn(sv - bf2f(h));
  }
  if (i < 1024) flags[i] = 0;
}

// ---------------------------------------------------------------------------
// Kernel C: persistent recurrence (64 workers) + DVFS heaters (192 blocks).
//
// Protocol = the verified system-scope ladder, with two latency micro-opts:
//  * per-WAVE flags: each wave drains its own stores (vmcnt(0)) and lane 0
//    posts flags[blk*16+wave]=t immediately — no slowest-wave wait before
//    posting. Consumers read one dwordx4 = all 4 wave-flags of a producer.
//    Correctness: a wave's flag=t still implies its reads(t) and stores(t)
//    are complete (program order through both barriers + drain). Stores at
//    t+1 still happen after BOTH barriers, i.e. after all 4 waves' polls —
//    the all-64-blocks union that makes double-buffer WAR safe is unchanged.
//  * depth-2 pipelined poll: two flag loads in flight, halving detection
//    quantization (each iteration previously cost a full serialized LLC RT).
// Heaters: blocks 64..255 burn dependent FMAs + touch LLC lightly until
// worker 0 posts its final wave-flags; bounded by the workers' (verified)
// termination, no sync coupling in the other direction.
// ---------------------------------------------------------------------------
__global__ __launch_bounds__(256, 1) void esn_rec(
    const float* __restrict__ w_res, const float* __restrict__ rn,
    float* __restrict__ out, unsigned short* __restrict__ st_hi,
    unsigned short* __restrict__ st_lo, int* flags) {
  __shared__ float pLDS[4 * 32 * 17];   // 8704 B [wave][row32][col16 pad17]

  const int tid = threadIdx.x;
  const int bx = blockIdx.x;

  // ---------------- heater path (blocks 64..255) ----------------
  if (bx >= NWORK) {
    float hx = (float)(tid + bx);
    const char* wb = (const char*)w_res;
    int it = 0;
    while (true) {
      i32x4 f;
      asm volatile("global_load_dwordx4 %0, %1, %2 sc0 sc1\n\ts_waitcnt vmcnt(0)"
                   : "=v"(f) : "v"(0), "s"(flags) : "memory");
      if (imin(imin(f.x, f.y), imin(f.z, f.w)) >= T_ - 1) break;
#pragma unroll 8
      for (int u = 0; u < 1024; ++u)
        hx = __builtin_fmaf(hx, 1.0000001f, 1.0e-7f);
      f32x4 dummy;
      int off = (it & 16383) * 256;     // rotate through w_res (4 MB, LLC)
      asm volatile("global_load_dwordx4 %0, %1, %2 sc0\n\ts_waitcnt vmcnt(0)"
                   : "=v"(dummy) : "v"(off), "s"(wb) : "memory");
      asm volatile("" :: "v"(dummy));
      ++it;
    }
    asm volatile("" :: "v"(hx));
    return;
  }

  // ---------------- worker path (blocks 0..63) ----------------
  const int blk = bx;
  const int lane = tid & 63, wave = tid >> 6;
  const int quad = lane >> 4, lm = lane & 15;

  // one-time: gather loop-invariant W fragments into registers (hi/lo split).
  // element j of fragment kk: w_res[k][c], k = wave*256+kk*32+quad*8+j,
  // c = blk*16+lm  — identical values to the verified LDS path.
  bf16x8 BH[8], BL[8];
#pragma unroll
  for (int kk = 0; kk < 8; ++kk) {
    const float* wp = w_res + (size_t)(wave * 256 + kk * 32 + quad * 8) * N_
                            + blk * CPB + lm;
    bf16x8 hv, lv;
#pragma unroll
    for (int j = 0; j < 8; ++j) {
      float wv = wp[(size_t)j * N_];
      unsigned short h = f2bf_rn(wv);
      hv[j] = (short)h;
      lv[j] = (short)f2bf_rn(wv - bf2f(h));
    }
    BH[kk] = hv;
    BL[kk] = lv;
  }

  // epilogue mapping: thread owns (row rm, cols cp, cp+1)
  const int rm = tid >> 3;               // 0..31
  const int cp = (tid & 7) * 2;          // 0,2,..,14
  const int colg = blk * CPB + cp;
  float2 nz = *(const float2*)&rn[(size_t)rm * N_ + colg];
  nz.x *= NOISE_; nz.y *= NOISE_;

  // byte voffsets for the wave's state fragments (rows lm and lm+16)
  const int vo0 = lm * 2048 + wave * 512 + quad * 16;
  const int vo1 = vo0 + 16 * 2048;
  // wave w needs k-slice [256w,256w+256) => producers 16w+p, p = lane&15.
  // One dwordx4 at byte (16w+p)*64 = that producer's 4 wave-flags.
  const int fbyte = (wave * 16 + (lane & 15)) * 64;

  for (int t = 1; t < T_; ++t) {
    const int pc = (t - 1) & 1, ncur = t & 1;

    // xin prefetch (own slot), pinned asm so vmcnt counts stay exact
    size_t o0 = ((size_t)rm * T_ + t) * N_ + colg;
    f32x2 xv;
    {
      int loff = (int)(o0 * 4);
      asm volatile("global_load_dwordx2 %0, %1, %2"
                   : "=v"(xv) : "v"(loff), "s"((const char*)out) : "memory");
    }

    // depth-2 pipelined quad poll (system scope)
    {
      const int need = t - 1;
      i32x4 fA, fB;
      asm volatile("global_load_dwordx4 %0, %1, %2 sc0 sc1"
                   : "=v"(fA) : "v"(fbyte), "s"(flags) : "memory");
      asm volatile("global_load_dwordx4 %0, %1, %2 sc0 sc1"
                   : "=v"(fB) : "v"(fbyte), "s"(flags) : "memory");
      while (true) {
        asm volatile("s_waitcnt vmcnt(1)" ::: "memory");
        __builtin_amdgcn_sched_barrier(0);
        if (__all(imin(imin(fA.x, fA.y), imin(fA.z, fA.w)) >= need)) break;
        asm volatile("global_load_dwordx4 %0, %1, %2 sc0 sc1"
                     : "=v"(fA) : "v"(fbyte), "s"(flags) : "memory");
        asm volatile("s_waitcnt vmcnt(1)" ::: "memory");
        __builtin_amdgcn_sched_barrier(0);
        if (__all(imin(imin(fB.x, fB.y), imin(fB.z, fB.w)) >= need)) break;
        asm volatile("global_load_dwordx4 %0, %1, %2 sc0 sc1"
                     : "=v"(fB) : "v"(fbyte), "s"(flags) : "memory");
      }
      asm volatile("s_waitcnt vmcnt(0)" ::: "memory");
      __builtin_amdgcn_sched_barrier(0);
    }

    // state fragment loads: verified sc0 sc1 form, all 32 in flight
    const char* baseH = (const char*)(st_hi + pc * (B_ * N_));
    const char* baseL = (const char*)(st_lo + pc * (B_ * N_));
    bf16x8 AH0[8], AH1[8], AL0[8], AL1[8];
#pragma unroll
    for (int kk = 0; kk < 8; ++kk) {
      int oa = vo0 + kk * 64, ob = vo1 + kk * 64;
      asm volatile("global_load_dwordx4 %0, %1, %2 sc0 sc1"
                   : "=v"(AH0[kk]) : "v"(oa), "s"(baseH) : "memory");
      asm volatile("global_load_dwordx4 %0, %1, %2 sc0 sc1"
                   : "=v"(AH1[kk]) : "v"(ob), "s"(baseH) : "memory");
      asm volatile("global_load_dwordx4 %0, %1, %2 sc0 sc1"
                   : "=v"(AL0[kk]) : "v"(oa), "s"(baseL) : "memory");
      asm volatile("global_load_dwordx4 %0, %1, %2 sc0 sc1"
                   : "=v"(AL1[kk]) : "v"(ob), "s"(baseL) : "memory");
    }

    f32x4 acc0 = {0.f, 0.f, 0.f, 0.f};   // rows 0-15
    f32x4 acc1 = {0.f, 0.f, 0.f, 0.f};   // rows 16-31

    // first half (kk 0..3 = oldest 16 loads) ready at vmcnt(16)
    asm volatile("s_waitcnt vmcnt(16)" ::: "memory");
    __builtin_amdgcn_sched_barrier(0);   // rule #18
#pragma unroll
    for (int kk = 0; kk < 4; ++kk) {
      acc0 = __builtin_amdgcn_mfma_f32_16x16x32_bf16(AH0[kk], BH[kk], acc0, 0, 0, 0);
      acc1 = __builtin_amdgcn_mfma_f32_16x16x32_bf16(AH1[kk], BH[kk], acc1, 0, 0, 0);
      acc0 = __builtin_amdgcn_mfma_f32_16x16x32_bf16(AL0[kk], BH[kk], acc0, 0, 0, 0);
      acc1 = __builtin_amdgcn_mfma_f32_16x16x32_bf16(AL1[kk], BH[kk], acc1, 0, 0, 0);
      acc0 = __builtin_amdgcn_mfma_f32_16x16x32_bf16(AH0[kk], BL[kk], acc0, 0, 0, 0);
      acc1 = __builtin_amdgcn_mfma_f32_16x16x32_bf16(AH1[kk], BL[kk], acc1, 0, 0, 0);
    }
    asm volatile("s_waitcnt vmcnt(0)" ::: "memory");
    __builtin_amdgcn_sched_barrier(0);
#pragma unroll
    for (int kk = 4; kk < 8; ++kk) {
      acc0 = __builtin_amdgcn_mfma_f32_16x16x32_bf16(AH0[kk], BH[kk], acc0, 0, 0, 0);
      acc1 = __builtin_amdgcn_mfma_f32_16x16x32_bf16(AH1[kk], BH[kk], acc1, 0, 0, 0);
      acc0 = __builtin_amdgcn_mfma_f32_16x16x32_bf16(AL0[kk], BH[kk], acc0, 0, 0, 0);
      acc1 = __builtin_amdgcn_mfma_f32_16x16x32_bf16(AL1[kk], BH[kk], acc1, 0, 0, 0);
      acc0 = __builtin_amdgcn_mfma_f32_16x16x32_bf16(AH0[kk], BL[kk], acc0, 0, 0, 0);
      acc1 = __builtin_amdgcn_mfma_f32_16x16x32_bf16(AH1[kk], BL[kk], acc1, 0, 0, 0);
    }

    // write K-partials: C frag layout row=quad*4+r, col=lm
#pragma unroll
    for (int r = 0; r < 4; ++r) {
      pLDS[wave * 544 + (quad * 4 + r) * 17 + lm]      = acc0[r];
      pLDS[wave * 544 + (quad * 4 + r + 16) * 17 + lm] = acc1[r];
    }
    __syncthreads();   // barrier 1: pLDS RAW

    // reduce 4 K-partials for (rm, cp) and (rm, cp+1)
    float sa = pLDS[0 * 544 + rm * 17 + cp] + pLDS[1 * 544 + rm * 17 + cp]
             + pLDS[2 * 544 + rm * 17 + cp] + pLDS[3 * 544 + rm * 17 + cp];
    float sb = pLDS[0 * 544 + rm * 17 + cp + 1] + pLDS[1 * 544 + rm * 17 + cp + 1]
             + pLDS[2 * 544 + rm * 17 + cp + 1] + pLDS[3 * 544 + rm * 17 + cp + 1];
    __syncthreads();   // barrier 2: pLDS WAR (early position — tail runs per-wave)

    float v0 = tanhf(sa + xv[0]) + nz.x;
    float v1 = tanhf(sb + xv[1]) + nz.y;
    float2 ov; ov.x = v0; ov.y = v1;
    *(float2*)&out[o0] = ov;

    // publish compensated bf16 state (verified __hip_atomic SYSTEM stores)
    unsigned short h0 = f2bf_rn(v0), h1 = f2bf_rn(v1);
    unsigned short l0 = f2bf_rn(v0 - bf2f(h0)), l1 = f2bf_rn(v1 - bf2f(h1));
    unsigned int hpack = (unsigned int)h0 | ((unsigned int)h1 << 16);
    unsigned int lpack = (unsigned int)l0 | ((unsigned int)l1 << 16);
    unsigned int* dh = (unsigned int*)(st_hi + ncur * (B_ * N_) + (size_t)rm * N_ + colg);
    unsigned int* dl = (unsigned int*)(st_lo + ncur * (B_ * N_) + (size_t)rm * N_ + colg);
    __hip_atomic_store(dh, hpack, __ATOMIC_RELAXED, __HIP_MEMORY_SCOPE_SYSTEM);
    __hip_atomic_store(dl, lpack, __ATOMIC_RELAXED, __HIP_MEMORY_SCOPE_SYSTEM);

    // per-wave drain, then lane 0 posts THIS wave's flag immediately
    asm volatile("s_waitcnt vmcnt(0)" ::: "memory");
    if (lane == 0) {
      asm volatile("global_store_dword %0, %1, %2 sc0 sc1"
                   :: "v"((blk * 16 + wave) * 4), "v"(t), "s"(flags) : "memory");
    }
  }
}

// ---------------------------------------------------------------------------
extern "C" void kernel_launch(void* const* d_in, const int* in_sizes, int n_in,
                              void* d_out, int out_size, void* d_ws, size_t ws_size,
                              hipStream_t stream) {
  const float* x       = (const float*)d_in[0];
  const float* w_in    = (const float*)d_in[1];
  const float* w_res   = (const float*)d_in[2];
  const float* wscale  = (const float*)d_in[3];
  const float* states0 = (const float*)d_in[4];
  const float* step0   = (const float*)d_in[5];
  const float* rnoise  = (const float*)d_in[6];
  float* out = (float*)d_out;

  char* ws = (char*)d_ws;
  unsigned short* st_hi = (unsigned short*)ws;                 // 131072 B
  unsigned short* st_lo = (unsigned short*)(ws + 131072);      // 131072 B
  int* flags            = (int*)(ws + 262144);                 // 4096 B

  xin_gemm<<<dim3(256, 16), 256, 0, stream>>>(x, w_in, wscale, out);
  init_k<<<128, 256, 0, stream>>>(states0, step0, out, st_hi, st_lo, flags);
  esn_rec<<<GRID_REC, 256, 0, stream>>>(w_res, rnoise, out, st_hi, st_lo, flags);
}

// Round 7
// 3205.325 us; speedup vs baseline: 1.0505x; 1.0505x over previous
//
#include <hip/hip_runtime.h>
#include <hip/hip_bf16.h>
#include <math.h>

// Problem dims
#define B_  32
#define T_  512
#define D_  128
#define N_  1024
#define NOISE_ 0.001f

#define NWORK 64            // recurrence blocks; each owns N_/NWORK = 16 columns
#define CPB   16
#define SLOT_BYTES 131072   // 32 rows * 256 packet-groups * 16 B

typedef __attribute__((ext_vector_type(8))) short  bf16x8;
typedef __attribute__((ext_vector_type(4))) float  f32x4;
typedef __attribute__((ext_vector_type(4))) int    i32x4;

static __device__ __forceinline__ unsigned short f2bf_rn(float f) {
    unsigned int u = __builtin_bit_cast(unsigned int, f);
    unsigned int r = (u + 0x7FFFu + ((u >> 16) & 1u)) >> 16;
    return (unsigned short)r;
}
static __device__ __forceinline__ float bf2f(unsigned short h) {
    return __builtin_bit_cast(float, (unsigned int)h << 16);
}

// ---------------------------------------------------------------------------
// Kernel A: xin = (x @ w_input) * scale, written INTO d_out at [b][t][n].
// (unchanged, verified)
// ---------------------------------------------------------------------------
__global__ __launch_bounds__(256) void xin_gemm(
    const float* __restrict__ x, const float* __restrict__ w_in,
    const float* __restrict__ scale_p, float* __restrict__ out) {
  __shared__ float As[64 * 132];
  __shared__ float Bs[128 * 68];
  const int tid = threadIdx.x;
  const int bm = blockIdx.x;       // 0..255
  const int bn = blockIdx.y;       // 0..15

  {
    const f32x4* xg = (const f32x4*)(x + (size_t)bm * 64 * 128);
#pragma unroll
    for (int i = 0; i < 8; ++i) {
      int idx = tid + i * 256;
      int r = idx >> 5, c4 = idx & 31;
      f32x4 v = xg[idx];
      float* dst = &As[r * 132 + c4 * 4];
      dst[0] = v.x; dst[1] = v.y; dst[2] = v.z; dst[3] = v.w;
    }
  }
  {
#pragma unroll
    for (int i = 0; i < 8; ++i) {
      int idx = tid + i * 256;
      int r = idx >> 4, c4 = idx & 15;
      f32x4 v = *(const f32x4*)(w_in + (size_t)r * N_ + bn * 64 + c4 * 4);
      float* dst = &Bs[r * 68 + c4 * 4];
      dst[0] = v.x; dst[1] = v.y; dst[2] = v.z; dst[3] = v.w;
    }
  }
  __syncthreads();

  const int tx = tid & 15, ty = tid >> 4;
  float acc[4][4] = {};
  for (int k = 0; k < 128; ++k) {
    float a0 = As[(ty * 4 + 0) * 132 + k];
    float a1 = As[(ty * 4 + 1) * 132 + k];
    float a2 = As[(ty * 4 + 2) * 132 + k];
    float a3 = As[(ty * 4 + 3) * 132 + k];
    f32x4 bv = *(const f32x4*)&Bs[k * 68 + tx * 4];
#pragma unroll
    for (int j = 0; j < 4; ++j) {
      acc[0][j] += a0 * bv[j];
      acc[1][j] += a1 * bv[j];
      acc[2][j] += a2 * bv[j];
      acc[3][j] += a3 * bv[j];
    }
  }
  const float s = scale_p[0];
#pragma unroll
  for (int i = 0; i < 4; ++i) {
    int row = bm * 64 + ty * 4 + i;
    if ((row & 511) == 0) continue;
    f32x4 o;
    o.x = acc[i][0] * s; o.y = acc[i][1] * s;
    o.z = acc[i][2] * s; o.w = acc[i][3] * s;
    *(f32x4*)(out + (size_t)row * N_ + bn * 64 + tx * 4) = o;
  }
}

// ---------------------------------------------------------------------------
// Kernel B: out[:,0,:] = step0 ; states0 -> packetized compensated-bf16
// buffer slot 0 (tag t=0); slot 1 filled with tag=2 (never matches t=1's
// expected tag=1, so garbage can't be accepted). Packet = 16 B =
// {hi01, lo01, hi23, lo23} covering 4 columns; LSB of each lo bf16 carries
// the step tag (lo of even col: bit t&1; odd col: bit (t>>1)&1).
// ---------------------------------------------------------------------------
__global__ __launch_bounds__(256) void init_k(
    const float* __restrict__ states0, const float* __restrict__ step0,
    float* __restrict__ out, char* __restrict__ stp) {
  int i = blockIdx.x * 256 + threadIdx.x;
  if (i < B_ * N_) {
    int b = i >> 10, n = i & 1023;
    out[((size_t)b * T_ + 0) * N_ + n] = step0[i];
  }
  if (i < B_ * N_ / 4) {            // 8192 packets per slot
    int r = i >> 8, g = i & 255;
    const float* sp = states0 + (size_t)r * N_ + g * 4;
    unsigned int hw[4], lw[4];
#pragma unroll
    for (int j = 0; j < 4; ++j) {
      float sv = sp[j];
      unsigned short h = f2bf_rn(sv);
      unsigned short l = f2bf_rn(sv - bf2f(h));
      hw[j] = h;
      lw[j] = (unsigned int)(l & 0xFFFEu);   // tag(t=0): both bits 0
    }
    i32x4 pkt;
    pkt.x = (int)(hw[0] | (hw[1] << 16));
    pkt.y = (int)(lw[0] | (lw[1] << 16));
    pkt.z = (int)(hw[2] | (hw[3] << 16));
    pkt.w = (int)(lw[2] | (lw[3] << 16));
    *(i32x4*)(stp + (size_t)i * 16) = pkt;
    i32x4 f1; f1.x = 0; f1.y = 0x00010000; f1.z = 0; f1.w = 0x00010000; // tag=2
    *(i32x4*)(stp + SLOT_BYTES + (size_t)i * 16) = f1;
  }
}

// ---------------------------------------------------------------------------
// Kernel C: persistent recurrence, FLAG-FREE self-validating protocol.
// Per step: cheap tag probe (1 dword per producer-sample) -> one full
// speculative packet sweep with tag validation (retry if any stale) -> MFMA
// -> pLDS reduce -> tanh -> single atomic dwordx4 packet store per 4 cols
// (sc0 sc1 write-through). No drains, no flag stores, no flag polls.
// WAR safety: a block stores step t only after all 4 waves validated ALL
// producers' t-1 packets (barrier union = 64 blocks), which implies every
// block consumed its t-2 reads of the slot being overwritten. Tag period 4
// (2 bits across the two lo LSBs of each dword pair) rejects +/-2-step
// aliasing. 16B aligned stores/loads are single-copy atomic -> fresh tag
// implies fresh packet. hi parts bit-exact vs verified kernel; lo parts
// perturbed <= 1 ulp(lo) ~ 2^-16 rel (absmax budget 0.0039).
// ---------------------------------------------------------------------------
__global__ __launch_bounds__(256, 1) void esn_rec(
    const float* __restrict__ w_res, const float* __restrict__ rn,
    float* __restrict__ out, char* stp) {
  __shared__ float pLDS[4 * 32 * 17];   // 8704 B [wave][row32][col16 pad17]

  const int tid = threadIdx.x;
  const int blk = blockIdx.x;           // 0..63
  const int lane = tid & 63, wave = tid >> 6;
  const int quad = lane >> 4, lm = lane & 15;

  // one-time: gather loop-invariant W fragments into registers (hi/lo split).
  bf16x8 BH[8], BL[8];
#pragma unroll
  for (int kk = 0; kk < 8; ++kk) {
    const float* wp = w_res + (size_t)(wave * 256 + kk * 32 + quad * 8) * N_
                            + blk * CPB + lm;
    bf16x8 hv, lv;
#pragma unroll
    for (int j = 0; j < 8; ++j) {
      float wv = wp[(size_t)j * N_];
      unsigned short h = f2bf_rn(wv);
      hv[j] = (short)h;
      lv[j] = (short)f2bf_rn(wv - bf2f(h));
    }
    BH[kk] = hv;
    BL[kk] = lv;
  }

  // epilogue mapping: thread owns (row rm, cols cp, cp+1)
  const int rm = tid >> 3;               // 0..31
  const int cp = (tid & 7) * 2;          // 0,2,..,14
  const int colg = blk * CPB + cp;
  float2 nz = *(const float2*)&rn[(size_t)rm * N_ + colg];
  nz.x *= NOISE_; nz.y *= NOISE_;

  // consumer packet byte offsets: row lm, packet pair per kk (row stride 4 KB)
  const int vo0 = lm * 4096 + wave * 1024 + quad * 32;
  const int vo1 = vo0 + 16 * 4096;       // row lm+16
  // probe: producer p = wave*16 + (lane&15); sample rows 7/15/23/31
  const int pp = wave * 16 + (lane & 15);
  const int pbyte = ((lane >> 4) * 8 + 7) * 4096 + (pp * 4 + (lane >> 4)) * 16 + 4;
  // producer store offset (even threads store one packet = 4 cols)
  const int so = rm * 4096 + (blk * 4 + (cp >> 2)) * 16;

  for (int t = 1; t < T_; ++t) {
    const char* slotR = stp + ((t - 1) & 1) * SLOT_BYTES;
    char* slotW = stp + (t & 1) * SLOT_BYTES;
    const int want = ((t - 1) & 1) | ((((t - 1) >> 1) & 1) << 16);

    // xin prefetch (own slot; written by xin_gemm, read+overwritten by us)
    size_t o0 = ((size_t)rm * T_ + t) * N_ + colg;
    float2 xv = *(const float2*)&out[o0];

    // cheap tag probe: 1 dword per (producer, sample row)
    {
      int pr;
      do {
        asm volatile("global_load_dword %0, %1, %2 sc0 sc1\n\ts_waitcnt vmcnt(0)"
                     : "=v"(pr) : "v"(pbyte), "s"(slotR) : "memory");
      } while (!__all((pr & 0x00010001) == want));
    }

    // full speculative sweep with validation (retry until all fresh)
    i32x4 PA[8], PB[8], PC[8], PD[8];
    while (true) {
#pragma unroll
      for (int kk = 0; kk < 8; ++kk) {
        int oa = vo0 + kk * 128, ob = vo1 + kk * 128;
        asm volatile("global_load_dwordx4 %0, %1, %2 sc0 sc1"
                     : "=v"(PA[kk]) : "v"(oa), "s"(slotR) : "memory");
        asm volatile("global_load_dwordx4 %0, %1, %2 sc0 sc1"
                     : "=v"(PB[kk]) : "v"(oa + 16), "s"(slotR) : "memory");
        asm volatile("global_load_dwordx4 %0, %1, %2 sc0 sc1"
                     : "=v"(PC[kk]) : "v"(ob), "s"(slotR) : "memory");
        asm volatile("global_load_dwordx4 %0, %1, %2 sc0 sc1"
                     : "=v"(PD[kk]) : "v"(ob + 16), "s"(slotR) : "memory");
      }
      asm volatile("s_waitcnt vmcnt(0)" ::: "memory");
      __builtin_amdgcn_sched_barrier(0);   // rule #18: nothing hoists past wait
      int err = 0;
#pragma unroll
      for (int kk = 0; kk < 8; ++kk) {
        err |= (PA[kk].y ^ want) | (PA[kk].w ^ want);
        err |= (PB[kk].y ^ want) | (PB[kk].w ^ want);
        err |= (PC[kk].y ^ want) | (PC[kk].w ^ want);
        err |= (PD[kk].y ^ want) | (PD[kk].w ^ want);
      }
      if (__all((err & 0x00010001) == 0)) break;
    }

    f32x4 acc0 = {0.f, 0.f, 0.f, 0.f};   // rows 0-15
    f32x4 acc1 = {0.f, 0.f, 0.f, 0.f};   // rows 16-31
#pragma unroll
    for (int kk = 0; kk < 8; ++kk) {
      i32x4 h0i, l0i, h1i, l1i;
      h0i.x = PA[kk].x; h0i.y = PA[kk].z; h0i.z = PB[kk].x; h0i.w = PB[kk].z;
      l0i.x = PA[kk].y; l0i.y = PA[kk].w; l0i.z = PB[kk].y; l0i.w = PB[kk].w;
      h1i.x = PC[kk].x; h1i.y = PC[kk].z; h1i.z = PD[kk].x; h1i.w = PD[kk].z;
      l1i.x = PC[kk].y; l1i.y = PC[kk].w; l1i.z = PD[kk].y; l1i.w = PD[kk].w;
      bf16x8 AH0 = __builtin_bit_cast(bf16x8, h0i);
      bf16x8 AL0 = __builtin_bit_cast(bf16x8, l0i);
      bf16x8 AH1 = __builtin_bit_cast(bf16x8, h1i);
      bf16x8 AL1 = __builtin_bit_cast(bf16x8, l1i);
      acc0 = __builtin_amdgcn_mfma_f32_16x16x32_bf16(AH0, BH[kk], acc0, 0, 0, 0);
      acc1 = __builtin_amdgcn_mfma_f32_16x16x32_bf16(AH1, BH[kk], acc1, 0, 0, 0);
      acc0 = __builtin_amdgcn_mfma_f32_16x16x32_bf16(AL0, BH[kk], acc0, 0, 0, 0);
      acc1 = __builtin_amdgcn_mfma_f32_16x16x32_bf16(AL1, BH[kk], acc1, 0, 0, 0);
      acc0 = __builtin_amdgcn_mfma_f32_16x16x32_bf16(AH0, BL[kk], acc0, 0, 0, 0);
      acc1 = __builtin_amdgcn_mfma_f32_16x16x32_bf16(AH1, BL[kk], acc1, 0, 0, 0);
    }

    // write K-partials: C frag layout row=quad*4+r, col=lm
#pragma unroll
    for (int r = 0; r < 4; ++r) {
      pLDS[wave * 544 + (quad * 4 + r) * 17 + lm]      = acc0[r];
      pLDS[wave * 544 + (quad * 4 + r + 16) * 17 + lm] = acc1[r];
    }
    __syncthreads();   // barrier 1: pLDS RAW (also completes the all-64 union)

    // reduce 4 K-partials for (rm, cp) and (rm, cp+1)
    float sa = pLDS[0 * 544 + rm * 17 + cp] + pLDS[1 * 544 + rm * 17 + cp]
             + pLDS[2 * 544 + rm * 17 + cp] + pLDS[3 * 544 + rm * 17 + cp];
    float sb = pLDS[0 * 544 + rm * 17 + cp + 1] + pLDS[1 * 544 + rm * 17 + cp + 1]
             + pLDS[2 * 544 + rm * 17 + cp + 1] + pLDS[3 * 544 + rm * 17 + cp + 1];
    __syncthreads();   // barrier 2: pLDS WAR

    float v0 = tanhf(sa + xv.x) + nz.x;
    float v1 = tanhf(sb + xv.y) + nz.y;
    float2 ov; ov.x = v0; ov.y = v1;
    *(float2*)&out[o0] = ov;

    // build + publish self-validating packet (even threads: cols cp..cp+3)
    float pv0 = __shfl_xor(v0, 1);
    float pv1 = __shfl_xor(v1, 1);
    if ((tid & 1) == 0) {
      unsigned int b0 = (unsigned int)(t & 1), b1 = (unsigned int)((t >> 1) & 1);
      unsigned short h0 = f2bf_rn(v0),  h1 = f2bf_rn(v1);
      unsigned short h2 = f2bf_rn(pv0), h3 = f2bf_rn(pv1);
      unsigned int l0 = ((unsigned int)f2bf_rn(v0  - bf2f(h0)) & 0xFFFEu) | b0;
      unsigned int l1 = ((unsigned int)f2bf_rn(v1  - bf2f(h1)) & 0xFFFEu) | b1;
      unsigned int l2 = ((unsigned int)f2bf_rn(pv0 - bf2f(h2)) & 0xFFFEu) | b0;
      unsigned int l3 = ((unsigned int)f2bf_rn(pv1 - bf2f(h3)) & 0xFFFEu) | b1;
      i32x4 pkt;
      pkt.x = (int)((unsigned int)h0 | ((unsigned int)h1 << 16));
      pkt.y = (int)(l0 | (l1 << 16));
      pkt.z = (int)((unsigned int)h2 | ((unsigned int)h3 << 16));
      pkt.w = (int)(l2 | (l3 << 16));
      asm volatile("global_store_dwordx4 %0, %1, %2 sc0 sc1"
                   :: "v"(so), "v"(pkt), "s"(slotW) : "memory");
    }
    // no drain, no flag — the packet tags ARE the handshake
  }
}

// ---------------------------------------------------------------------------
extern "C" void kernel_launch(void* const* d_in, const int* in_sizes, int n_in,
                              void* d_out, int out_size, void* d_ws, size_t ws_size,
                              hipStream_t stream) {
  const float* x       = (const float*)d_in[0];
  const float* w_in    = (const float*)d_in[1];
  const float* w_res   = (const float*)d_in[2];
  const float* wscale  = (const float*)d_in[3];
  const float* states0 = (const float*)d_in[4];
  const float* step0   = (const float*)d_in[5];
  const float* rnoise  = (const float*)d_in[6];
  float* out = (float*)d_out;

  char* stp = (char*)d_ws;   // 2 slots x 128 KiB packetized state

  xin_gemm<<<dim3(256, 16), 256, 0, stream>>>(x, w_in, wscale, out);
  init_k<<<128, 256, 0, stream>>>(states0, step0, out, stp);
  esn_rec<<<NWORK, 256, 0, stream>>>(w_res, rnoise, out, stp);
}